// Round 3
// baseline (90.122 us; speedup 1.0000x reference)
//
#include <hip/hip_runtime.h>

#define D4    80      // float4 per x row (D=320)
#define DIM1  10
#define DIM2  5
#define BLK   256     // 4 waves
#define RPI   8       // rows per block-iter (4 waves x 2 rows)
#define ITERS 20
#define CROWS (RPI * ITERS)   // 160 t-rows incl. +-2 halo
#define OROWS (CROWS - 4)     // 156 output rows per block (156 % 4 == 0 -> aligned float4 out)

// 16-lane (DPP row) butterfly-free ring reduction: v += ror8(v); v += ror4(v); ...
// Pure VALU - no LDS pipe, no lgkmcnt.
__device__ __forceinline__ float row16_sum(float v) {
    int p;
    p = __builtin_amdgcn_update_dpp(0, __float_as_int(v), 0x128, 0xF, 0xF, true); // row_ror:8
    v += __int_as_float(p);
    p = __builtin_amdgcn_update_dpp(0, __float_as_int(v), 0x124, 0xF, 0xF, true); // row_ror:4
    v += __int_as_float(p);
    p = __builtin_amdgcn_update_dpp(0, __float_as_int(v), 0x122, 0xF, 0xF, true); // row_ror:2
    v += __int_as_float(p);
    p = __builtin_amdgcn_update_dpp(0, __float_as_int(v), 0x121, 0xF, 0xF, true); // row_ror:1
    v += __int_as_float(p);
    return v;
}

// Per 32-lane row-group: s = lane&15 (K-slot, 20 floats interleaved as 5x float4
// at stride 16), half = (lane>>4)&1 (d in [half*5, half*5+5)).
// W1 slice register-resident: 25 float4 = 100 VGPR/lane (3200 floats / 32 lanes).
__global__ __launch_bounds__(BLK, 3)
void fused_fcl_win(const float4* __restrict__ x4,
                   const float4* __restrict__ w1g,   // W1 as float4[10*80]
                   const float*  __restrict__ w2,    // [5][10]
                   const float*  __restrict__ b2,    // [5]
                   float*        __restrict__ out,
                   int N)
{
    __shared__ float t_lds[CROWS * DIM2];   // 800 floats = 3.2 KB

    const int tid  = threadIdx.x;
    const int lane = tid & 63;
    const int wave = tid >> 6;
    const int s    = lane & 15;
    const int half = (lane >> 4) & 1;
    const int slot = wave * 2 + (lane >> 5);   // row slot within iter (0..7)

    // one-time register-resident W1 slice (L2-resident after first blocks)
    float4 w1r[5][5];
    {
        const float4* wp = w1g + (half * 5) * D4 + s;
        #pragma unroll
        for (int dd = 0; dd < 5; ++dd)
            #pragma unroll
            for (int i = 0; i < 5; ++i)
                w1r[dd][i] = wp[dd * D4 + i * 16];
    }

    // this lane's W2 slice: channel j = s (s<5), d in this lane's half only
    const int j = (s < DIM2) ? s : 0;
    float w2h[5];
    #pragma unroll
    for (int dd = 0; dd < 5; ++dd)
        w2h[dd] = w2[j * DIM1 + half * 5 + dd];
    const float b2r = b2[j];

    const int base = (int)blockIdx.x * OROWS;

    #pragma unroll 2
    for (int it = 0; it < ITERS; ++it) {
        const int r  = base - 2 + it * RPI + slot;
        const int rc = min(max(r, 0), N - 1);        // clamp keeps load legal
        const float4* xp = x4 + (size_t)rc * D4 + s;

        float4 xv[5];
        #pragma unroll
        for (int i = 0; i < 5; ++i) xv[i] = xp[i * 16];

        // layer 1 (this lane's 5 d's) + layer-2 partial, all in VALU
        float partial = 0.f;
        #pragma unroll
        for (int dd = 0; dd < 5; ++dd) {
            float acc = 0.f;
            #pragma unroll
            for (int i = 0; i < 5; ++i) {
                float4 a  = w1r[dd][i];
                float4 xx = xv[i];
                acc += xx.x * a.x; acc += xx.y * a.y;
                acc += xx.z * a.z; acc += xx.w * a.w;
            }
            acc = row16_sum(acc);              // full dot in all 16 lanes (DPP)
            partial += fmaxf(acc, 0.f) * w2h[dd];
        }
        // combine the two d-halves: one ds op per iter
        const float other = __shfl_xor(partial, 16);
        float t5 = fmaxf(b2r + partial + other, 0.f);
        if (r < 0 || r >= N) t5 = 0.f;         // zero-pad window semantics
        if (half == 0 && s < DIM2)
            t_lds[(it * RPI + slot) * DIM2 + s] = t5;
    }
    __syncthreads();

    // window expansion: out[n, a*5+jj] = t[n+a-2, jj]
    // flat: e = nr*25 + c  ->  t_lds idx = nr*5 + c  (= e - 20*nr)
    const int lim = min(OROWS, N - base);
    const int nf  = lim * 25;
    float*    ob  = out + (size_t)base * 25;   // 16B-aligned (base % 4 == 0)
    const int nf4 = nf >> 2;
    for (int f = tid; f < nf4; f += BLK) {
        int e  = f * 4;
        int nr = e / 25;                       // magic-mul div
        int c  = e - nr * 25;
        int idx = nr * 5 + c;
        float v[4];
        #pragma unroll
        for (int u = 0; u < 4; ++u) {
            v[u] = t_lds[idx];
            ++c; ++idx;
            if (c == 25) { c = 0; idx -= 20; }
        }
        *(float4*)(ob + e) = make_float4(v[0], v[1], v[2], v[3]);
    }
    for (int e = (nf & ~3) + tid; e < nf; e += BLK) {   // tail (rare)
        int nr = e / 25;
        ob[e] = t_lds[e - 20 * nr];
    }
}

extern "C" void kernel_launch(void* const* d_in, const int* in_sizes, int n_in,
                              void* d_out, int out_size, void* d_ws, size_t ws_size,
                              hipStream_t stream)
{
    const float4* x4 = (const float4*)d_in[0];
    const float4* w1 = (const float4*)d_in[1];
    const float*  w2 = (const float*)d_in[2];
    const float*  b2 = (const float*)d_in[3];

    const int N = in_sizes[0] / 320;   // 200000
    float* out = (float*)d_out;

    const int grid = (N + OROWS - 1) / OROWS;   // 1283 blocks
    fused_fcl_win<<<grid, BLK, 0, stream>>>(x4, w1, w2, b2, out, N);
}

// Round 5
// 56.801 us; speedup vs baseline: 1.5866x; 1.5866x over previous
//
#include <hip/hip_runtime.h>

#define D4    80      // float4 per x row (D=320)
#define DIM1  10
#define DIM2  5
#define BLK   256     // 4 waves
#define RPI   8       // rows per block-iter (4 waves x 2 rows)
#define ITERS 10
#define CROWS (RPI * ITERS)   // 80 t-rows incl. +-2 halo
#define OROWS (CROWS - 4)     // 76 output rows (76*25 % 4 == 0 -> aligned float4 out)

typedef float __attribute__((ext_vector_type(4))) f32x4;  // native vec for nontemporal builtins

// 16-lane sum via DPP row_ror (pure VALU pipe, no lgkmcnt). Validated R3.
__device__ __forceinline__ float row16_sum(float v) {
    int p;
    p = __builtin_amdgcn_update_dpp(0, __float_as_int(v), 0x128, 0xF, 0xF, true); // row_ror:8
    v += __int_as_float(p);
    p = __builtin_amdgcn_update_dpp(0, __float_as_int(v), 0x124, 0xF, 0xF, true); // row_ror:4
    v += __int_as_float(p);
    p = __builtin_amdgcn_update_dpp(0, __float_as_int(v), 0x122, 0xF, 0xF, true); // row_ror:2
    v += __int_as_float(p);
    p = __builtin_amdgcn_update_dpp(0, __float_as_int(v), 0x121, 0xF, 0xF, true); // row_ror:1
    v += __int_as_float(p);
    return v;
}

// Per 32-lane row-group: s = lane&15 (K-slot: 5 float4 at stride 16),
// half = (lane>>4)&1 (d in [half*5, half*5+5)). W1 slice reg-resident
// (100 VGPR/lane). Hot loop: 5 nt global_load_dwordx4 + 100 FMA + 20 DPP
// + 1 ds_swizzle per row.
__global__ __launch_bounds__(BLK, 2)
void fused_fcl_win(const f32x4* __restrict__ x4,
                   const f32x4* __restrict__ w1g,    // W1 as float4[10*80]
                   const float* __restrict__ w2,     // [5][10]
                   const float* __restrict__ b2,     // [5]
                   float*       __restrict__ out,
                   int N)
{
    __shared__ float t_lds[CROWS * DIM2];   // 400 floats = 1.6 KB

    const int tid  = threadIdx.x;
    const int lane = tid & 63;
    const int wave = tid >> 6;
    const int s    = lane & 15;
    const int half = (lane >> 4) & 1;
    const int slot = wave * 2 + (lane >> 5);   // row slot within iter (0..7)

    // one-time register-resident W1 slice (reused across blocks -> L2-resident)
    f32x4 w1r[5][5];
    {
        const f32x4* wp = w1g + (half * 5) * D4 + s;
        #pragma unroll
        for (int dd = 0; dd < 5; ++dd)
            #pragma unroll
            for (int i = 0; i < 5; ++i)
                w1r[dd][i] = wp[dd * D4 + i * 16];
    }

    // this lane's W2 slice: channel j = s (s<5), d's of this lane's half only
    const int j = (s < DIM2) ? s : 0;
    float w2h[5];
    #pragma unroll
    for (int dd = 0; dd < 5; ++dd)
        w2h[dd] = w2[j * DIM1 + half * 5 + dd];
    const float b2r = b2[j];

    const int base = (int)blockIdx.x * OROWS;

    auto loadrow = [&](int it, f32x4* xv) {
        int r  = base - 2 + it * RPI + slot;
        int rc = min(max(r, 0), N - 1);          // clamp keeps load legal
        const f32x4* xp = x4 + (size_t)rc * D4 + s;
        #pragma unroll
        for (int i = 0; i < 5; ++i)
            xv[i] = __builtin_nontemporal_load(xp + i * 16);  // streaming, no-allocate
    };

    f32x4 xv[5];
    loadrow(0, xv);

    for (int it = 0; it < ITERS; ++it) {
        // 1-deep prefetch: next row's loads in flight during this row's compute
        f32x4 xn[5];
        if (it + 1 < ITERS) loadrow(it + 1, xn);

        float partial = 0.f;
        #pragma unroll
        for (int dd = 0; dd < 5; ++dd) {
            float acc = 0.f;
            #pragma unroll
            for (int i = 0; i < 5; ++i) {
                f32x4 a  = w1r[dd][i];
                f32x4 xx = xv[i];
                acc += xx.x * a.x; acc += xx.y * a.y;
                acc += xx.z * a.z; acc += xx.w * a.w;
            }
            acc = row16_sum(acc);                 // full dot in all 16 lanes
            partial += fmaxf(acc, 0.f) * w2h[dd]; // layer-2 partial (this half)
        }
        // combine halves: single cross-lane op per row
        const float other = __shfl_xor(partial, 16);
        float t5 = fmaxf(b2r + partial + other, 0.f);

        const int r = base - 2 + it * RPI + slot;
        if (r < 0 || r >= N) t5 = 0.f;            // zero-pad window semantics
        if (half == 0 && s < DIM2)
            t_lds[(it * RPI + slot) * DIM2 + s] = t5;

        #pragma unroll
        for (int i = 0; i < 5; ++i) xv[i] = xn[i];
    }
    __syncthreads();

    // window expansion: out[n, a*5+jj] = t[n+a-2, jj]; flat e=nr*25+c -> lds idx e-20*nr
    const int lim = min(OROWS, N - base);
    const int nf  = lim * 25;
    float*    ob  = out + (size_t)base * 25;      // 16B-aligned (76*25 % 4 == 0)
    const int nf4 = nf >> 2;
    for (int f = tid; f < nf4; f += BLK) {
        int e   = f * 4;
        int nr  = e / 25;
        int c   = e - nr * 25;
        int idx = nr * 5 + c;
        float v[4];
        #pragma unroll
        for (int u = 0; u < 4; ++u) {
            v[u] = t_lds[idx];
            ++c; ++idx;
            if (c == 25) { c = 0; idx -= 20; }
        }
        f32x4 vv = { v[0], v[1], v[2], v[3] };
        __builtin_nontemporal_store(vv, (f32x4*)(ob + e));
    }
    for (int e = (nf & ~3) + tid; e < nf; e += BLK) {   // tail (none when lim*25%4==0)
        int nr = e / 25;
        ob[e] = t_lds[e - 20 * nr];
    }
}

extern "C" void kernel_launch(void* const* d_in, const int* in_sizes, int n_in,
                              void* d_out, int out_size, void* d_ws, size_t ws_size,
                              hipStream_t stream)
{
    const f32x4* x4 = (const f32x4*)d_in[0];
    const f32x4* w1 = (const f32x4*)d_in[1];
    const float* w2 = (const float*)d_in[2];
    const float* b2 = (const float*)d_in[3];

    const int N = in_sizes[0] / 320;   // 200000
    float* out = (float*)d_out;

    const int grid = (N + OROWS - 1) / OROWS;   // 2632 blocks
    fused_fcl_win<<<grid, BLK, 0, stream>>>(x4, w1, w2, b2, out, N);
}

// Round 6
// 56.701 us; speedup vs baseline: 1.5894x; 1.0018x over previous
//
#include <hip/hip_runtime.h>

#define D4    80      // float4 per x row (D=320)
#define DIM1  10
#define DIM2  5
#define BLK   256     // 4 waves
#define RPI   16      // rows per block-iter (4 waves x 4 rows)
#define ITERS 10
#define CROWS (RPI * ITERS)   // 160 t-rows incl. +-2 halo
#define OROWS (CROWS - 4)     // 156 output rows per block
#define NREG  4               // W1 rows (d) held in registers per lane
#define NLDS  (DIM1 - NREG)   // 6 W1 rows read from LDS

typedef float __attribute__((ext_vector_type(4))) f32x4;

// 16-lane sum via DPP row_ror (pure VALU, no lgkmcnt). Validated R3/R5.
__device__ __forceinline__ float row16_sum(float v) {
    int p;
    p = __builtin_amdgcn_update_dpp(0, __float_as_int(v), 0x128, 0xF, 0xF, true); // row_ror:8
    v += __int_as_float(p);
    p = __builtin_amdgcn_update_dpp(0, __float_as_int(v), 0x124, 0xF, 0xF, true); // row_ror:4
    v += __int_as_float(p);
    p = __builtin_amdgcn_update_dpp(0, __float_as_int(v), 0x122, 0xF, 0xF, true); // row_ror:2
    v += __int_as_float(p);
    p = __builtin_amdgcn_update_dpp(0, __float_as_int(v), 0x121, 0xF, 0xF, true); // row_ror:1
    v += __int_as_float(p);
    return v;
}

__device__ __forceinline__ float dot4(f32x4 a, f32x4 b) {
    return a.x * b.x + a.y * b.y + a.z * b.z + a.w * b.w;
}

// Per wave: 4 rows x 16 lanes. s = lane&15 (K-slot: 5 f4 at stride 16),
// g = lane>>4 (row in quad). All 64 lanes load DISTINCT x float4s.
// W1: d<4 in regs (80 VGPR), d>=4 from LDS (2-way bank alias = free).
// After row16_sum every lane holds h_d -> lane s<5 emits channel s directly.
__global__ __launch_bounds__(BLK, 3)
void fused_fcl_win(const f32x4* __restrict__ x4,
                   const f32x4* __restrict__ w1g,    // W1 as f4[10*80]
                   const float* __restrict__ w2,     // [5][10]
                   const float* __restrict__ b2,     // [5]
                   float*       __restrict__ out,
                   int N)
{
    __shared__ f32x4 w1s[NLDS * D4];        // 480 f4 = 7.68 KB
    __shared__ float t_lds[CROWS * DIM2];   // 800 floats = 3.2 KB

    const int tid  = threadIdx.x;
    const int lane = tid & 63;
    const int wave = tid >> 6;
    const int s    = lane & 15;
    const int g    = lane >> 4;
    const int slot = wave * 4 + g;          // row slot within iter (0..15)

    // stage W1[d=NREG..9] to LDS (one-time)
    for (int f = tid; f < NLDS * D4; f += BLK)
        w1s[f] = w1g[NREG * D4 + f];

    // register-resident W1[d=0..NREG-1] slice for this lane's K-slot
    f32x4 w1r[NREG][5];
    #pragma unroll
    for (int dd = 0; dd < NREG; ++dd)
        #pragma unroll
        for (int i = 0; i < 5; ++i)
            w1r[dd][i] = w1g[dd * D4 + s + 16 * i];

    // lane s<5 owns output channel s: full W2 row + bias
    const int j = (s < DIM2) ? s : 0;
    float w2r[DIM1];
    #pragma unroll
    for (int d = 0; d < DIM1; ++d) w2r[d] = w2[j * DIM1 + d];
    const float b2r = b2[j];

    __syncthreads();

    const int base = (int)blockIdx.x * OROWS;

    auto loadrow = [&](int it, f32x4* xv) {
        int r  = base - 2 + it * RPI + slot;
        int rc = min(max(r, 0), N - 1);      // clamp keeps load legal
        const f32x4* xp = x4 + (size_t)rc * D4 + s;
        #pragma unroll
        for (int i = 0; i < 5; ++i)
            xv[i] = __builtin_nontemporal_load(xp + i * 16);  // streaming
    };

    f32x4 xv[5];
    loadrow(0, xv);

    int wofs = 0;   // opaque LDS f4-offset: blocks LICM from hoisting W1 reads
    for (int it = 0; it < ITERS; ++it) {
        f32x4 xn[5];
        if (it + 1 < ITERS) loadrow(it + 1, xn);   // 1-deep prefetch

        asm volatile("" : "+v"(wofs));

        float partial = b2r;
        #pragma unroll
        for (int dd = 0; dd < NREG; ++dd) {
            float acc = 0.f;
            #pragma unroll
            for (int i = 0; i < 5; ++i) acc += dot4(w1r[dd][i], xv[i]);
            acc = row16_sum(acc);
            partial += fmaxf(acc, 0.f) * w2r[dd];
        }
        #pragma unroll
        for (int dd = 0; dd < NLDS; ++dd) {
            float acc = 0.f;
            #pragma unroll
            for (int i = 0; i < 5; ++i) {
                f32x4 w = w1s[wofs + dd * D4 + s + 16 * i];  // 2-way alias: free
                acc += dot4(w, xv[i]);
            }
            acc = row16_sum(acc);
            partial += fmaxf(acc, 0.f) * w2r[NREG + dd];
        }
        float t5 = fmaxf(partial, 0.f);

        const int r = base - 2 + it * RPI + slot;
        if (r < 0 || r >= N) t5 = 0.f;       // zero-pad window semantics
        if (s < DIM2)
            t_lds[(it * RPI + slot) * DIM2 + s] = t5;

        #pragma unroll
        for (int i = 0; i < 5; ++i) xv[i] = xn[i];
    }
    __syncthreads();

    // window expansion: out[n, a*5+jj] = t[n+a-2, jj]; flat e=nr*25+c -> lds idx e-20*nr
    const int lim = min(OROWS, N - base);
    const int nf  = lim * 25;
    float*    ob  = out + (size_t)base * 25;   // 16B-aligned (156*25 % 4 == 0)
    const int nf4 = nf >> 2;
    for (int f = tid; f < nf4; f += BLK) {
        int e   = f * 4;
        int nr  = e / 25;
        int c   = e - nr * 25;
        int idx = nr * 5 + c;
        float v[4];
        #pragma unroll
        for (int u = 0; u < 4; ++u) {
            v[u] = t_lds[idx];
            ++c; ++idx;
            if (c == 25) { c = 0; idx -= 20; }
        }
        f32x4 vv = { v[0], v[1], v[2], v[3] };
        __builtin_nontemporal_store(vv, (f32x4*)(ob + e));
    }
    for (int e = (nf & ~3) + tid; e < nf; e += BLK) {   // tail (last block only)
        int nr = e / 25;
        ob[e] = t_lds[e - 20 * nr];
    }
}

extern "C" void kernel_launch(void* const* d_in, const int* in_sizes, int n_in,
                              void* d_out, int out_size, void* d_ws, size_t ws_size,
                              hipStream_t stream)
{
    const f32x4* x4 = (const f32x4*)d_in[0];
    const f32x4* w1 = (const f32x4*)d_in[1];
    const float* w2 = (const float*)d_in[2];
    const float* b2 = (const float*)d_in[3];

    const int N = in_sizes[0] / 320;   // 200000
    float* out = (float*)d_out;

    const int grid = (N + OROWS - 1) / OROWS;   // 1283 blocks
    fused_fcl_win<<<grid, BLK, 0, stream>>>(x4, w1, w2, b2, out, N);
}

// Round 7
// 53.965 us; speedup vs baseline: 1.6700x; 1.0507x over previous
//
#include <hip/hip_runtime.h>

#define D4    80      // float4 per x row (D=320)
#define DIM1  10
#define DIM2  5
#define BLK   256     // 4 waves
#define RPI   16      // rows per block-iter (4 waves x 4 rows)
#define ITERS 12
#define CROWS (RPI * ITERS)   // 192 t-rows incl. +-2 halo
#define OROWS (CROWS - 4)     // 188 output rows per block
#define NREG  4               // W1 rows (d) held in registers per lane
#define NLDS  (DIM1 - NREG)   // 6 W1 rows read from LDS

typedef float __attribute__((ext_vector_type(4))) f32x4;

// 16-lane sum via DPP row_ror (pure VALU, no lgkmcnt). Validated R3/R5/R6.
__device__ __forceinline__ float row16_sum(float v) {
    int p;
    p = __builtin_amdgcn_update_dpp(0, __float_as_int(v), 0x128, 0xF, 0xF, true); // row_ror:8
    v += __int_as_float(p);
    p = __builtin_amdgcn_update_dpp(0, __float_as_int(v), 0x124, 0xF, 0xF, true); // row_ror:4
    v += __int_as_float(p);
    p = __builtin_amdgcn_update_dpp(0, __float_as_int(v), 0x122, 0xF, 0xF, true); // row_ror:2
    v += __int_as_float(p);
    p = __builtin_amdgcn_update_dpp(0, __float_as_int(v), 0x121, 0xF, 0xF, true); // row_ror:1
    v += __int_as_float(p);
    return v;
}

__device__ __forceinline__ float dot4(f32x4 a, f32x4 b) {
    return a.x * b.x + a.y * b.y + a.z * b.z + a.w * b.w;
}

// Per wave: 4 rows x 16 lanes. s = lane&15 (K-slot: 5 f4 at stride 16),
// g = lane>>4 (row in quad). All 64 lanes load DISTINCT x float4s.
// W1: d<4 in regs (80 VGPR), d>=4 from LDS (2-way bank alias = free).
// After row16_sum every lane holds h_d -> lane s<5 emits channel s directly.
__global__ __launch_bounds__(BLK, 3)
void fused_fcl_win(const f32x4* __restrict__ x4,
                   const f32x4* __restrict__ w1g,    // W1 as f4[10*80]
                   const float* __restrict__ w2,     // [5][10]
                   const float* __restrict__ b2,     // [5]
                   float*       __restrict__ out,
                   int N)
{
    __shared__ f32x4 w1s[NLDS * D4];        // 480 f4 = 7.68 KB
    __shared__ float t_lds[CROWS * DIM2];   // 960 floats = 3.84 KB

    const int tid  = threadIdx.x;
    const int lane = tid & 63;
    const int wave = tid >> 6;
    const int s    = lane & 15;
    const int g    = lane >> 4;
    const int slot = wave * 4 + g;          // row slot within iter (0..15)

    // stage W1[d=NREG..9] to LDS (one-time)
    for (int f = tid; f < NLDS * D4; f += BLK)
        w1s[f] = w1g[NREG * D4 + f];

    // register-resident W1[d=0..NREG-1] slice for this lane's K-slot
    f32x4 w1r[NREG][5];
    #pragma unroll
    for (int dd = 0; dd < NREG; ++dd)
        #pragma unroll
        for (int i = 0; i < 5; ++i)
            w1r[dd][i] = w1g[dd * D4 + s + 16 * i];

    // lane s<5 owns output channel s: full W2 row + bias
    const int j = (s < DIM2) ? s : 0;
    float w2r[DIM1];
    #pragma unroll
    for (int d = 0; d < DIM1; ++d) w2r[d] = w2[j * DIM1 + d];
    const float b2r = b2[j];

    __syncthreads();

    const int base = (int)blockIdx.x * OROWS;

    auto loadrow = [&](int it, f32x4* xv) {
        int r  = base - 2 + it * RPI + slot;
        int rc = min(max(r, 0), N - 1);      // clamp keeps load legal
        const f32x4* xp = x4 + (size_t)rc * D4 + s;
        #pragma unroll
        for (int i = 0; i < 5; ++i)
            xv[i] = xp[i * 16];              // plain loads (nt removed: A/B vs R6)
    };

    f32x4 xv[5];
    loadrow(0, xv);

    int wofs = 0;   // opaque LDS f4-offset: blocks LICM from hoisting W1 reads
    for (int it = 0; it < ITERS; ++it) {
        f32x4 xn[5];
        if (it + 1 < ITERS) loadrow(it + 1, xn);   // 1-deep prefetch

        asm volatile("" : "+v"(wofs));

        float partial = b2r;
        #pragma unroll
        for (int dd = 0; dd < NREG; ++dd) {
            float acc = 0.f;
            #pragma unroll
            for (int i = 0; i < 5; ++i) acc += dot4(w1r[dd][i], xv[i]);
            acc = row16_sum(acc);
            partial += fmaxf(acc, 0.f) * w2r[dd];
        }
        #pragma unroll
        for (int dd = 0; dd < NLDS; ++dd) {
            float acc = 0.f;
            #pragma unroll
            for (int i = 0; i < 5; ++i) {
                f32x4 w = w1s[wofs + dd * D4 + s + 16 * i];  // 2-way alias: free
                acc += dot4(w, xv[i]);
            }
            acc = row16_sum(acc);
            partial += fmaxf(acc, 0.f) * w2r[NREG + dd];
        }
        float t5 = fmaxf(partial, 0.f);

        const int r = base - 2 + it * RPI + slot;
        if (r < 0 || r >= N) t5 = 0.f;       // zero-pad window semantics
        if (s < DIM2)
            t_lds[(it * RPI + slot) * DIM2 + s] = t5;

        #pragma unroll
        for (int i = 0; i < 5; ++i) xv[i] = xn[i];
    }
    __syncthreads();

    // window expansion: out[n, a*5+jj] = t[n+a-2, jj]; flat e=nr*25+c -> lds idx e-20*nr
    const int lim = min(OROWS, N - base);
    const int nf  = lim * 25;
    float*    ob  = out + (size_t)base * 25;   // 16B-aligned (188*25 % 4 == 0)
    const int nf4 = nf >> 2;
    for (int f = tid; f < nf4; f += BLK) {
        int e   = f * 4;
        int nr  = e / 25;
        int c   = e - nr * 25;
        int idx = nr * 5 + c;
        float v[4];
        #pragma unroll
        for (int u = 0; u < 4; ++u) {
            v[u] = t_lds[idx];
            ++c; ++idx;
            if (c == 25) { c = 0; idx -= 20; }
        }
        f32x4 vv = { v[0], v[1], v[2], v[3] };
        __builtin_nontemporal_store(vv, (f32x4*)(ob + e));
    }
    for (int e = (nf & ~3) + tid; e < nf; e += BLK) {   // tail (last block only)
        int nr = e / 25;
        ob[e] = t_lds[e - 20 * nr];
    }
}

extern "C" void kernel_launch(void* const* d_in, const int* in_sizes, int n_in,
                              void* d_out, int out_size, void* d_ws, size_t ws_size,
                              hipStream_t stream)
{
    const f32x4* x4 = (const f32x4*)d_in[0];
    const f32x4* w1 = (const f32x4*)d_in[1];
    const float* w2 = (const float*)d_in[2];
    const float* b2 = (const float*)d_in[3];

    const int N = in_sizes[0] / 320;   // 200000
    float* out = (float*)d_out;

    const int grid = (N + OROWS - 1) / OROWS;   // 1064 blocks
    fused_fcl_win<<<grid, BLK, 0, stream>>>(x4, w1, w2, b2, out, N);
}

// Round 8
// 50.319 us; speedup vs baseline: 1.7910x; 1.0724x over previous
//
#include <hip/hip_runtime.h>

#define D4    80      // float4 per x row (D=320)
#define DIM1  10
#define DIM2  5
#define BLK   256     // 4 waves
#define RPI   16      // rows per block-iter (4 waves x 4 rows)
#define ITERS 17
#define CROWS (RPI * ITERS)   // 272 t-rows computed (incl. +-2 halo, zero round-up waste)
#define OROWS (CROWS - 4)     // 268 output rows per block; 268*25 % 4 == 0 (aligned f4 stores)
#define NREG  4               // W1 rows (d) held in registers per lane
#define NLDS  (DIM1 - NREG)   // 6 W1 rows read from LDS

typedef float __attribute__((ext_vector_type(4))) f32x4;

// 16-lane sum via DPP row_ror (pure VALU, no lgkmcnt). Validated R3/R5/R6/R7.
__device__ __forceinline__ float row16_sum(float v) {
    int p;
    p = __builtin_amdgcn_update_dpp(0, __float_as_int(v), 0x128, 0xF, 0xF, true); // row_ror:8
    v += __int_as_float(p);
    p = __builtin_amdgcn_update_dpp(0, __float_as_int(v), 0x124, 0xF, 0xF, true); // row_ror:4
    v += __int_as_float(p);
    p = __builtin_amdgcn_update_dpp(0, __float_as_int(v), 0x122, 0xF, 0xF, true); // row_ror:2
    v += __int_as_float(p);
    p = __builtin_amdgcn_update_dpp(0, __float_as_int(v), 0x121, 0xF, 0xF, true); // row_ror:1
    v += __int_as_float(p);
    return v;
}

__device__ __forceinline__ float dot4(f32x4 a, f32x4 b) {
    return a.x * b.x + a.y * b.y + a.z * b.z + a.w * b.w;
}

// Per wave: 4 rows x 16 lanes. s = lane&15 (K-slot: 5 f4 at stride 16),
// g = lane>>4 (row in quad). All 64 lanes load DISTINCT x float4s.
// W1: d<4 in regs (80 VGPR), d>=4 from LDS (broadcast/2-way alias = free).
// Grid = 747 blocks <= 768 co-resident capacity -> single uniform round.
__global__ __launch_bounds__(BLK, 3)
void fused_fcl_win(const f32x4* __restrict__ x4,
                   const f32x4* __restrict__ w1g,    // W1 as f4[10*80]
                   const float* __restrict__ w2,     // [5][10]
                   const float* __restrict__ b2,     // [5]
                   float*       __restrict__ out,
                   int N)
{
    __shared__ f32x4 w1s[NLDS * D4];        // 480 f4 = 7.68 KB
    __shared__ float t_lds[CROWS * DIM2];   // 1360 floats = 5.44 KB

    const int tid  = threadIdx.x;
    const int lane = tid & 63;
    const int wave = tid >> 6;
    const int s    = lane & 15;
    const int g    = lane >> 4;
    const int slot = wave * 4 + g;          // row slot within iter (0..15)

    // stage W1[d=NREG..9] to LDS (one-time per block, amortized over 17 iters)
    for (int f = tid; f < NLDS * D4; f += BLK)
        w1s[f] = w1g[NREG * D4 + f];

    // register-resident W1[d=0..NREG-1] slice for this lane's K-slot
    f32x4 w1r[NREG][5];
    #pragma unroll
    for (int dd = 0; dd < NREG; ++dd)
        #pragma unroll
        for (int i = 0; i < 5; ++i)
            w1r[dd][i] = w1g[dd * D4 + s + 16 * i];

    // lane s<5 owns output channel s: full W2 row + bias
    const int j = (s < DIM2) ? s : 0;
    float w2r[DIM1];
    #pragma unroll
    for (int d = 0; d < DIM1; ++d) w2r[d] = w2[j * DIM1 + d];
    const float b2r = b2[j];

    __syncthreads();

    const int base = (int)blockIdx.x * OROWS;

    auto loadrow = [&](int it, f32x4* xv) {
        int r  = base - 2 + it * RPI + slot;
        int rc = min(max(r, 0), N - 1);      // clamp keeps load legal
        const f32x4* xp = x4 + (size_t)rc * D4 + s;
        #pragma unroll
        for (int i = 0; i < 5; ++i)
            xv[i] = xp[i * 16];              // plain loads (nt hurt: R6->R7 A/B)
    };

    f32x4 xv[5];
    loadrow(0, xv);

    int wofs = 0;   // opaque LDS f4-offset: blocks LICM from hoisting W1 reads
    for (int it = 0; it < ITERS; ++it) {
        f32x4 xn[5];
        if (it + 1 < ITERS) loadrow(it + 1, xn);   // 1-deep prefetch

        asm volatile("" : "+v"(wofs));

        float partial = b2r;
        #pragma unroll
        for (int dd = 0; dd < NREG; ++dd) {
            float acc = 0.f;
            #pragma unroll
            for (int i = 0; i < 5; ++i) acc += dot4(w1r[dd][i], xv[i]);
            acc = row16_sum(acc);
            partial += fmaxf(acc, 0.f) * w2r[dd];
        }
        #pragma unroll
        for (int dd = 0; dd < NLDS; ++dd) {
            float acc = 0.f;
            #pragma unroll
            for (int i = 0; i < 5; ++i) {
                f32x4 w = w1s[wofs + dd * D4 + s + 16 * i];  // broadcast: free
                acc += dot4(w, xv[i]);
            }
            acc = row16_sum(acc);
            partial += fmaxf(acc, 0.f) * w2r[NREG + dd];
        }
        float t5 = fmaxf(partial, 0.f);

        const int r = base - 2 + it * RPI + slot;
        if (r < 0 || r >= N) t5 = 0.f;       // zero-pad window semantics
        if (s < DIM2)
            t_lds[(it * RPI + slot) * DIM2 + s] = t5;

        #pragma unroll
        for (int i = 0; i < 5; ++i) xv[i] = xn[i];
    }
    __syncthreads();

    // window expansion: out[n, a*5+jj] = t[n+a-2, jj]; flat e=nr*25+c -> lds idx e-20*nr
    const int lim = min(OROWS, N - base);
    const int nf  = lim * 25;
    float*    ob  = out + (size_t)base * 25;   // 16B-aligned (base*25 % 4 == 0)
    const int nf4 = nf >> 2;
    for (int f = tid; f < nf4; f += BLK) {
        int e   = f * 4;
        int nr  = e / 25;
        int c   = e - nr * 25;
        int idx = nr * 5 + c;
        float v[4];
        #pragma unroll
        for (int u = 0; u < 4; ++u) {
            v[u] = t_lds[idx];
            ++c; ++idx;
            if (c == 25) { c = 0; idx -= 20; }
        }
        f32x4 vv = { v[0], v[1], v[2], v[3] };
        __builtin_nontemporal_store(vv, (f32x4*)(ob + e));
    }
    for (int e = (nf & ~3) + tid; e < nf; e += BLK) {   // tail (last block only)
        int nr = e / 25;
        ob[e] = t_lds[e - 20 * nr];
    }
}

extern "C" void kernel_launch(void* const* d_in, const int* in_sizes, int n_in,
                              void* d_out, int out_size, void* d_ws, size_t ws_size,
                              hipStream_t stream)
{
    const f32x4* x4 = (const f32x4*)d_in[0];
    const f32x4* w1 = (const f32x4*)d_in[1];
    const float* w2 = (const float*)d_in[2];
    const float* b2 = (const float*)d_in[3];

    const int N = in_sizes[0] / 320;   // 200000
    float* out = (float*)d_out;

    const int grid = (N + OROWS - 1) / OROWS;   // 747 blocks <= 768 capacity
    fused_fcl_win<<<grid, BLK, 0, stream>>>(x4, w1, w2, b2, out, N);
}